// Round 5
// baseline (347.040 us; speedup 1.0000x reference)
//
#include <hip/hip_runtime.h>

#define NN 40000
#define NE 320000
#define C 256
#define KORD 5
#define KT 1280          // fused K = 5 * 256
// Slice-blocked state layout: elem (k, s, n, c) -> ((k*8+s)*40000 + n)*32 + c
//   k = Chebyshev order 0..4, s = channel slice 0..7 (32 ch), c = 0..31.
// One slice = 40000*64 B = 2.56 MB contiguous -> fits a 4 MB XCD L2.
// Flattened K order (k major, s, c) == old kt=k*256+ch order -> GEMM summation
// order identical to previous rounds (bit-identical output).

typedef __attribute__((ext_vector_type(8))) short short8;   // 8 x bf16 (4 VGPR)
typedef __attribute__((ext_vector_type(4))) float floatx4;  // 4 x f32
typedef unsigned short bf16_t;

#define SLICE_ELEMS 1280000   // 40000*32

__device__ __forceinline__ bf16_t f2bf(float f) {
    union { float f; unsigned u; } v; v.f = f;
    unsigned r = v.u + 0x7fffu + ((v.u >> 16) & 1u);  // RTNE
    return (bf16_t)(r >> 16);
}
__device__ __forceinline__ float bf2f(bf16_t h) {
    union { unsigned u; float f; } v; v.u = ((unsigned)h) << 16;
    return v.f;
}

#define GLL16(gsrc, ldst)                                                        \
    __builtin_amdgcn_global_load_lds(                                            \
        (const __attribute__((address_space(1))) void*)(gsrc),                   \
        (__attribute__((address_space(3))) void*)(ldst), 16, 0, 0)

// ---------------- graph preprocessing ----------------

__global__ void count_kernel(const int* __restrict__ ei,
                             int* __restrict__ deg_keep,
                             int* __restrict__ cnt_all) {
    int e = blockIdx.x * 256 + threadIdx.x;
    if (e >= NE) return;
    int r = ei[e];
    int c = ei[NE + e];
    atomicAdd(&cnt_all[r], 1);
    if (r != c) atomicAdd(&deg_keep[r], 1);
}

__global__ void scan1_kernel(const int* __restrict__ cnt,
                             int* __restrict__ incl,
                             int* __restrict__ bsum) {
    __shared__ int s[256];
    int t = threadIdx.x;
    int idx = blockIdx.x * 256 + t;
    int v = (idx < NN) ? cnt[idx] : 0;
    s[t] = v;
    __syncthreads();
    for (int off = 1; off < 256; off <<= 1) {
        int add = (t >= off) ? s[t - off] : 0;
        __syncthreads();
        s[t] += add;
        __syncthreads();
    }
    if (idx < NN) incl[idx] = s[t];
    if (t == 255) bsum[blockIdx.x] = s[255];
}

__global__ void scan2_kernel(int* __restrict__ bsum, int nb) {
    __shared__ int s[256];
    int t = threadIdx.x;
    int v = (t < nb) ? bsum[t] : 0;
    s[t] = v;
    __syncthreads();
    for (int off = 1; off < 256; off <<= 1) {
        int add = (t >= off) ? s[t - off] : 0;
        __syncthreads();
        s[t] += add;
        __syncthreads();
    }
    if (t < nb) bsum[t] = s[t] - v;   // exclusive
}

// scan3 + dis fused (one less launch)
__global__ void scan3_kernel(const int* __restrict__ cnt,
                             const int* __restrict__ incl,
                             const int* __restrict__ bexcl,
                             const int* __restrict__ deg,
                             float* __restrict__ dis,
                             int* __restrict__ row_ptr,
                             int* __restrict__ cursor) {
    int idx = blockIdx.x * 256 + threadIdx.x;
    if (idx == 0) row_ptr[NN] = NE;
    if (idx >= NN) return;
    int rp = incl[idx] - cnt[idx] + bexcl[blockIdx.x];
    row_ptr[idx] = rp;
    cursor[idx]  = rp;
    int d = deg[idx];
    dis[idx] = (d > 0) ? rsqrtf((float)d) : 0.0f;
}

__global__ void fill_kernel(const int* __restrict__ ei,
                            const float* __restrict__ ew,
                            const float* __restrict__ dis,
                            int* __restrict__ cursor,
                            int* __restrict__ csr_col,
                            float* __restrict__ csr_val) {
    int e = blockIdx.x * 256 + threadIdx.x;
    if (e >= NE) return;
    int r = ei[e];
    int c = ei[NE + e];
    int pos = atomicAdd(&cursor[r], 1);
    float w = (r != c) ? ew[e] : 0.0f;     // removed self-loops -> weight 0
    csr_col[pos] = c;
    csr_val[pos] = -dis[r] * w * dis[c];
}

// convert x (fp32 [NN][256]) into slice-blocked bf16 chunk k=0
// thread per (n, s, h): i = n*16 + s*2 + h ; reads 64 B, writes 32 B
__global__ void convx_kernel(const float* __restrict__ x, bf16_t* __restrict__ st) {
    int i = blockIdx.x * 256 + threadIdx.x;
    if (i >= NN * 16) return;
    int n = i >> 4, s = (i >> 1) & 7, h = i & 1;
    const float* xs = &x[(size_t)n * C + s * 32 + h * 16];
    bf16_t* o = st + (size_t)s * SLICE_ELEMS + (size_t)n * 32 + h * 16;
#pragma unroll
    for (int q = 0; q < 4; ++q) {
        float4 f = *(const float4*)&xs[q * 4];
        ushort4 hh;
        hh.x = f2bf(f.x); hh.y = f2bf(f.y); hh.z = f2bf(f.z); hh.w = f2bf(f.w);
        *(ushort4*)&o[q * 4] = hh;
    }
}

// transpose+convert W[5][256][256] -> WT[n(256)][kt(1280)] bf16 (row-major)
__global__ void wt_kernel(const float* __restrict__ W, bf16_t* __restrict__ WT) {
    int t = blockIdx.x * 256 + threadIdx.x;
    if (t >= 256 * KT) return;
    int n = t & 255, kt = t >> 8;
    WT[(size_t)n * KT + kt] = f2bf(W[(size_t)kt * 256 + n]);
}

// ---------------- SpMM (slice-blocked, XCD-pinned gathers) ----------------
// grid (8, 1250): blockIdx.x = slice s. linear block id = s + 8*by -> round-robin
// XCD assignment pins slice s to XCD s: gather working set = 2.56 MB, L2-hot.
// Each 8-lane group owns one row x 32 ch; lane keeps its 4 channels across all
// edges of the row -> NO cross-lane reduction. FP order per channel = j
// ascending (identical to previous rounds -> bit-identical results).
// out[n][slice] = bf16( alpha * sum_j val[j]*V[col[j]][slice] - (ksub>=0 ? sub) )
__global__ __launch_bounds__(256)
void spmm_kernel(bf16_t* __restrict__ st,
                 const int* __restrict__ row_ptr,
                 const int* __restrict__ csr_col,
                 const float* __restrict__ csr_val,
                 float alpha, int kin, int kout, int ksub) {
    int s = blockIdx.x;                       // channel slice 0..7
    int wave = threadIdx.x >> 6;
    int lane = threadIdx.x & 63;
    int r8 = lane >> 3, c8 = lane & 7;        // row-in-group, 8B-chunk
    int n = (blockIdx.y * 4 + wave) * 8 + r8; // grid.y*4*8 = 40000 exact
    int j0 = row_ptr[n];
    int j1 = row_ptr[n + 1];
    const bf16_t* V = st + (size_t)(kin * 8 + s) * SLICE_ELEMS;
    int co = c8 * 4;                          // my 4 channels within slice
    float a0 = 0.f, a1 = 0.f, a2 = 0.f, a3 = 0.f;
    int j = j0;
    for (; j + 2 <= j1; j += 2) {
        int   col0 = csr_col[j];     int   col1 = csr_col[j + 1];
        float w0   = csr_val[j];     float w1   = csr_val[j + 1];
        ushort4 v0 = *(const ushort4*)&V[(size_t)col0 * 32 + co];
        ushort4 v1 = *(const ushort4*)&V[(size_t)col1 * 32 + co];
        a0 += w0 * bf2f(v0.x); a1 += w0 * bf2f(v0.y);
        a2 += w0 * bf2f(v0.z); a3 += w0 * bf2f(v0.w);
        a0 += w1 * bf2f(v1.x); a1 += w1 * bf2f(v1.y);
        a2 += w1 * bf2f(v1.z); a3 += w1 * bf2f(v1.w);
    }
    if (j < j1) {
        int   col = csr_col[j];
        float w   = csr_val[j];
        ushort4 v = *(const ushort4*)&V[(size_t)col * 32 + co];
        a0 += w * bf2f(v.x); a1 += w * bf2f(v.y);
        a2 += w * bf2f(v.z); a3 += w * bf2f(v.w);
    }
    float r0, r1, r2, r3;
    if (ksub >= 0) {
        ushort4 sv = *(const ushort4*)&st[(size_t)(ksub * 8 + s) * SLICE_ELEMS
                                          + (size_t)n * 32 + co];
        r0 = alpha * a0 - bf2f(sv.x);
        r1 = alpha * a1 - bf2f(sv.y);
        r2 = alpha * a2 - bf2f(sv.z);
        r3 = alpha * a3 - bf2f(sv.w);
    } else {
        r0 = alpha * a0; r1 = alpha * a1; r2 = alpha * a2; r3 = alpha * a3;
    }
    ushort4 h;
    h.x = f2bf(r0); h.y = f2bf(r1); h.z = f2bf(r2); h.w = f2bf(r3);
    // wave writes 8 rows x 64 B = 512 B fully coalesced
    *(ushort4*)&st[(size_t)(kout * 8 + s) * SLICE_ELEMS + (size_t)n * 32 + co] = h;
}

// ---------------- fused bf16 MFMA GEMM (round-1 structure, at its byte floor) ----------------
// out[M=40000][256] = A @ WT^T + bias, A in slice-blocked layout.
// CONCLUSION r0-r3: all schedule/tile variants land at 44-46 us = 143 MB mixed
// HBM traffic at ~3.25 TB/s (mixed read+write achievable). Keep round-1 form
// (best mean). Only A-staging addresses changed for the slice-blocked layout;
// LDS logical layout, fragments, epilogue identical -> bit-identical output.
// K-window ki (64 ch) = slice pair (2ki, 2ki+1); granule g: chunk g>>2,
// 16B-quarter g&3. Per staging instr A touches 2 x 512 B contiguous runs.
__global__ __launch_bounds__(256, 2)
void gemm_mfma(const bf16_t* __restrict__ Abf,  // slice-blocked state
               const bf16_t* __restrict__ WT,   // [256][KT] row-major
               const float* __restrict__ bias,
               float* __restrict__ out) {
    __shared__ bf16_t smem[3][12288];  // per buf: As = [0,4096), Bs = [4096,12288)
    int tid = threadIdx.x;
    int w = tid >> 6, lane = tid & 63;
    int m0 = blockIdx.x * 64;
    int n0 = blockIdx.y * 128;
    int wm = w & 1, wn = w >> 1;
    int quad = lane >> 4, l16 = lane & 15, l7 = l16 & 7;

    // staging: 1536 granules of 16B per K-iter; wave w call j covers
    // granules gi = (w*6+j)*64 + lane. gi<512 -> A slot, else B slot.
    const bf16_t* srcbase[6];
    size_t strd[6];
#pragma unroll
    for (int j = 0; j < 6; ++j) {
        int gi = (w * 6 + j) * 64 + lane;           // 0..1535
        int isB = gi >= 512;
        int t  = isB ? gi - 512 : gi;
        int row = t >> 3;                           // A: 0..63, B: 0..127
        int pg = t & 7;
        int g  = pg ^ (row & 7);                    // source k-granule for this slot
        if (isB) {
            srcbase[j] = WT + (size_t)(n0 + row) * KT + g * 8;
            strd[j] = 64;
        } else {
            srcbase[j] = Abf + (size_t)(g >> 2) * SLICE_ELEMS
                             + (size_t)(m0 + row) * 32 + (g & 3) * 8;
            strd[j] = 2 * SLICE_ELEMS;
        }
    }

    int arowb = wm * 32 + l16;    // A fragment base row (mt adds 16)
    int browb = wn * 64 + l16;    // B fragment base row (nt adds 16)

    floatx4 acc[2][4] = {};

    const int NT = KT / 64;       // 20

    // prologue: issue tiles 0 and 1 (12 loads/wave outstanding)
#pragma unroll
    for (int j = 0; j < 6; ++j)
        GLL16(srcbase[j], &smem[0][(w * 6 + j) * 512]);
#pragma unroll
    for (int j = 0; j < 6; ++j)
        GLL16(srcbase[j] + strd[j], &smem[1][(w * 6 + j) * 512]);

    int bufc = 0;                 // buffer holding tile t
    for (int t = 0; t < NT; ++t) {
        // wait: tile t's 6 loads (oldest outstanding) have landed in LDS
        if (t < NT - 1) {
            asm volatile("s_waitcnt vmcnt(6)" ::: "memory");
        } else {
            asm volatile("s_waitcnt vmcnt(0)" ::: "memory");
        }
        __builtin_amdgcn_sched_barrier(0);
        __builtin_amdgcn_s_barrier();   // all waves: tile t landed; buf[(t-1)%3] reads done

        // issue tile t+2 into buf[(t+2)%3] (== buf[(t-1)%3], safe after barrier)
        if (t + 2 < NT) {
            int bnext = bufc + 2; if (bnext >= 3) bnext -= 3;
#pragma unroll
            for (int j = 0; j < 6; ++j)
                GLL16(srcbase[j] + (size_t)(t + 2) * strd[j],
                      &smem[bnext][(w * 6 + j) * 512]);
        }

        const bf16_t* sb = smem[bufc];
#pragma unroll
        for (int c = 0; c < 2; ++c) {              // two 32-k chunks inside BK=64
            int gp   = (c * 4 + quad) ^ l7;        // physical granule for this frag
            int aoff = (arowb * 8 + gp) * 8;
            int boff = 4096 + (browb * 8 + gp) * 8;
            short8 af[2], bfr[4];
#pragma unroll
            for (int mt = 0; mt < 2; ++mt) af[mt]  = *(const short8*)&sb[aoff + mt * 1024];
#pragma unroll
            for (int nt = 0; nt < 4; ++nt) bfr[nt] = *(const short8*)&sb[boff + nt * 1024];
#pragma unroll
            for (int mt = 0; mt < 2; ++mt)
#pragma unroll
                for (int nt = 0; nt < 4; ++nt)
                    acc[mt][nt] = __builtin_amdgcn_mfma_f32_16x16x32_bf16(
                        af[mt], bfr[nt], acc[mt][nt], 0, 0, 0);
        }

        bufc += 1; if (bufc == 3) bufc = 0;
    }

    // epilogue: C/D layout col=lane&15, row=quad*4+reg  (m89-verified)
#pragma unroll
    for (int nt = 0; nt < 4; ++nt) {
        int n = n0 + wn * 64 + nt * 16 + l16;
        float bv = bias[n];
#pragma unroll
        for (int mt = 0; mt < 2; ++mt) {
            int mbase = m0 + wm * 32 + mt * 16 + quad * 4;
#pragma unroll
            for (int r = 0; r < 4; ++r)
                out[(size_t)(mbase + r) * C + n] = acc[mt][nt][r] + bv;
        }
    }
}

// ---------------- launch ----------------

extern "C" void kernel_launch(void* const* d_in, const int* in_sizes, int n_in,
                              void* d_out, int out_size, void* d_ws, size_t ws_size,
                              hipStream_t stream) {
    const float* x    = (const float*)d_in[0];
    const int*   ei   = (const int*)d_in[1];
    const float* ew   = (const float*)d_in[2];
    const float* W    = (const float*)d_in[3];   // [5][256][256]
    const float* bias = (const float*)d_in[4];
    float* out = (float*)d_out;

    char* p = (char*)d_ws;
    auto carve = [&](size_t bytes) {
        char* q = p;
        p += (bytes + 255) & ~(size_t)255;
        return q;
    };
    int*    deg     = (int*)   carve(NN * 4);
    int*    cnt     = (int*)   carve(NN * 4);
    int*    incl    = (int*)   carve(NN * 4);
    int*    bsum    = (int*)   carve(256 * 4);
    int*    row_ptr = (int*)   carve((NN + 1) * 4);
    int*    cursor  = (int*)   carve(NN * 4);
    int*    csr_col = (int*)   carve(NE * 4);
    float*  csr_val = (float*) carve(NE * 4);
    float*  dis     = (float*) carve(NN * 4);
    bf16_t* abf     = (bf16_t*)carve((size_t)NN * KT * 2);   // slice-blocked bf16 state
    bf16_t* WT      = (bf16_t*)carve((size_t)C * KT * 2);    // W transposed bf16
    (void)ws_size; (void)n_in; (void)in_sizes; (void)out_size;

    const int NB_E = (NE + 255) / 256;   // 1250
    const int NB_N = (NN + 255) / 256;   // 157

    hipMemsetAsync(deg, 0, NN * 4, stream);
    hipMemsetAsync(cnt, 0, NN * 4, stream);

    count_kernel<<<NB_E, 256, 0, stream>>>(ei, deg, cnt);
    scan1_kernel<<<NB_N, 256, 0, stream>>>(cnt, incl, bsum);
    scan2_kernel<<<1, 256, 0, stream>>>(bsum, NB_N);
    scan3_kernel<<<NB_N, 256, 0, stream>>>(cnt, incl, bsum, deg, dis, row_ptr, cursor);
    fill_kernel<<<NB_E, 256, 0, stream>>>(ei, ew, dis, cursor, csr_col, csr_val);

    convx_kernel<<<(NN * 16 + 255) / 256, 256, 0, stream>>>(x, abf);
    wt_kernel<<<(256 * KT + 255) / 256, 256, 0, stream>>>(W, WT);

    // Chebyshev recursion in slice-blocked chunks 0..4; grid.x = slice -> XCD pin
    dim3 sgrid(8, NN / 32);   // (8, 1250)
    spmm_kernel<<<sgrid, 256, 0, stream>>>(abf, row_ptr, csr_col, csr_val,
                                           1.0f, 0, 1, -1);
    spmm_kernel<<<sgrid, 256, 0, stream>>>(abf, row_ptr, csr_col, csr_val,
                                           2.0f, 1, 2, 0);
    spmm_kernel<<<sgrid, 256, 0, stream>>>(abf, row_ptr, csr_col, csr_val,
                                           2.0f, 2, 3, 1);
    spmm_kernel<<<sgrid, 256, 0, stream>>>(abf, row_ptr, csr_col, csr_val,
                                           2.0f, 3, 4, 2);

    // fused GEMM: out = A @ WT^T + bias
    dim3 ggrid(625, 2);
    gemm_mfma<<<ggrid, 256, 0, stream>>>(abf, WT, bias, out);
}

// Round 6
// 316.647 us; speedup vs baseline: 1.0960x; 1.0960x over previous
//
#include <hip/hip_runtime.h>

#define NN 40000
#define NE 320000
#define C 256
#define KORD 5
#define KT 1280          // fused K = 5 * 256

typedef __attribute__((ext_vector_type(8))) short short8;    // 8 x bf16 (4 VGPR)
typedef __attribute__((ext_vector_type(8))) unsigned short ushort8;
typedef __attribute__((ext_vector_type(4))) float floatx4;   // 4 x f32
typedef unsigned short bf16_t;

__device__ __forceinline__ bf16_t f2bf(float f) {
    union { float f; unsigned u; } v; v.f = f;
    unsigned r = v.u + 0x7fffu + ((v.u >> 16) & 1u);  // RTNE
    return (bf16_t)(r >> 16);
}
__device__ __forceinline__ float bf2f(bf16_t h) {
    union { unsigned u; float f; } v; v.u = ((unsigned)h) << 16;
    return v.f;
}

#define GLL16(gsrc, ldst)                                                        \
    __builtin_amdgcn_global_load_lds(                                            \
        (const __attribute__((address_space(1))) void*)(gsrc),                   \
        (__attribute__((address_space(3))) void*)(ldst), 16, 0, 0)

// ---------------- graph preprocessing ----------------

__global__ void count_kernel(const int* __restrict__ ei,
                             int* __restrict__ deg_keep,
                             int* __restrict__ cnt_all) {
    int e = blockIdx.x * 256 + threadIdx.x;
    if (e >= NE) return;
    int r = ei[e];
    int c = ei[NE + e];
    atomicAdd(&cnt_all[r], 1);
    if (r != c) atomicAdd(&deg_keep[r], 1);
}

__global__ void scan1_kernel(const int* __restrict__ cnt,
                             int* __restrict__ incl,
                             int* __restrict__ bsum) {
    __shared__ int s[256];
    int t = threadIdx.x;
    int idx = blockIdx.x * 256 + t;
    int v = (idx < NN) ? cnt[idx] : 0;
    s[t] = v;
    __syncthreads();
    for (int off = 1; off < 256; off <<= 1) {
        int add = (t >= off) ? s[t - off] : 0;
        __syncthreads();
        s[t] += add;
        __syncthreads();
    }
    if (idx < NN) incl[idx] = s[t];
    if (t == 255) bsum[blockIdx.x] = s[255];
}

__global__ void scan2_kernel(int* __restrict__ bsum, int nb) {
    __shared__ int s[256];
    int t = threadIdx.x;
    int v = (t < nb) ? bsum[t] : 0;
    s[t] = v;
    __syncthreads();
    for (int off = 1; off < 256; off <<= 1) {
        int add = (t >= off) ? s[t - off] : 0;
        __syncthreads();
        s[t] += add;
        __syncthreads();
    }
    if (t < nb) bsum[t] = s[t] - v;   // exclusive
}

// scan3 + dis fused (one less launch)
__global__ void scan3_kernel(const int* __restrict__ cnt,
                             const int* __restrict__ incl,
                             const int* __restrict__ bexcl,
                             const int* __restrict__ deg,
                             float* __restrict__ dis,
                             int* __restrict__ row_ptr,
                             int* __restrict__ cursor) {
    int idx = blockIdx.x * 256 + threadIdx.x;
    if (idx == 0) row_ptr[NN] = NE;
    if (idx >= NN) return;
    int rp = incl[idx] - cnt[idx] + bexcl[blockIdx.x];
    row_ptr[idx] = rp;
    cursor[idx]  = rp;
    int d = deg[idx];
    dis[idx] = (d > 0) ? rsqrtf((float)d) : 0.0f;
}

__global__ void fill_kernel(const int* __restrict__ ei,
                            const float* __restrict__ ew,
                            const float* __restrict__ dis,
                            int* __restrict__ cursor,
                            int* __restrict__ csr_col,
                            float* __restrict__ csr_val) {
    int e = blockIdx.x * 256 + threadIdx.x;
    if (e >= NE) return;
    int r = ei[e];
    int c = ei[NE + e];
    int pos = atomicAdd(&cursor[r], 1);
    float w = (r != c) ? ew[e] : 0.0f;     // removed self-loops -> weight 0
    csr_col[pos] = c;
    csr_val[pos] = -dis[r] * w * dis[c];
}

// convert x (fp32 [NN][256]) into bf16 A-chunk 0 of [NN][KT]
__global__ void convx_kernel(const float* __restrict__ x, bf16_t* __restrict__ abf) {
    int i = blockIdx.x * 256 + threadIdx.x;
    if (i >= NN * 64) return;
    int n = i >> 6, cg = i & 63;
    float4 f = *(const float4*)&x[(size_t)n * C + cg * 4];
    ushort4 h;
    h.x = f2bf(f.x); h.y = f2bf(f.y); h.z = f2bf(f.z); h.w = f2bf(f.w);
    *(ushort4*)&abf[(size_t)n * KT + cg * 4] = h;
}

// transpose+convert W[5][256][256] -> WT[n(256)][kt(1280)] bf16
__global__ void wt_kernel(const float* __restrict__ W, bf16_t* __restrict__ WT) {
    int t = blockIdx.x * 256 + threadIdx.x;
    if (t >= 256 * KT) return;
    int n = t & 255, kt = t >> 8;
    WT[(size_t)n * KT + kt] = f2bf(W[(size_t)kt * 256 + n]);
}

// ---------------- SpMM (latency-optimized: 2 edges/instr, single predicated batch) ----------------
// outb[n][:] = bf16( alpha * sum_j val[j]*Vb[col[j]][:] - (use_sub ? subb[n][:] : 0) )
// One wave per row. Halves of the wave process even/odd edges: lane = half*32 + c,
// channel base cb = (lane&31)*8 -> 32 lanes x 16 B (ushort8) cover the 512 B row,
// so ONE batch issues 16 edges' gathers back-to-back (8 dwordx4 loads/lane,
// invalid edges clamped to j0 with weight 0). Poisson(8) degrees: 99.7% of rows
// need a single batch -> one gather-latency exposure per row (was: unroll-8/4/
// scalar cascade with serial ~600cy-per-edge tail). Cross-half reduce: one
// shfl_xor(32). FP note: per-row edge order is already nondeterministic (atomic
// cursor), and fp32 pairwise-vs-serial rounding is dominated by bf16 storage.
__global__ __launch_bounds__(256)
void spmm_kernel(const bf16_t* __restrict__ Vb,
                 const bf16_t* __restrict__ subb,
                 const int* __restrict__ row_ptr,
                 const int* __restrict__ csr_col,
                 const float* __restrict__ csr_val,
                 bf16_t* __restrict__ outb,
                 float alpha, int use_sub) {
    int wave = __builtin_amdgcn_readfirstlane(threadIdx.x >> 6);  // wave-uniform
    int lane = threadIdx.x & 63;
    int n = blockIdx.x * 4 + wave;          // grid is exactly NN/4 blocks
    int j0 = row_ptr[n];
    int j1 = row_ptr[n + 1];
    int half = lane >> 5;
    int cb = (lane & 31) * 8;               // 8 channels = 16 B per lane
    float a[8] = {};
    for (int jb = j0; jb < j1; jb += 16) {
        int cc[8]; float ww[8]; ushort8 vv[8];
#pragma unroll
        for (int u = 0; u < 8; ++u) {
            int je = jb + 2 * u + half;
            int ok = je < j1;
            int jc = ok ? je : j0;          // always in-bounds (loop ran => j0<j1)
            cc[u] = csr_col[jc];
            ww[u] = ok ? csr_val[jc] : 0.0f;
        }
#pragma unroll
        for (int u = 0; u < 8; ++u)
            vv[u] = *(const ushort8*)&Vb[(size_t)cc[u] * KT + cb];
#pragma unroll
        for (int u = 0; u < 8; ++u)
#pragma unroll
            for (int q = 0; q < 8; ++q)
                a[q] += ww[u] * bf2f(vv[u][q]);
    }
#pragma unroll
    for (int q = 0; q < 8; ++q)
        a[q] += __shfl_xor(a[q], 32);       // even-edge + odd-edge partials
    if (half == 0) {                        // 32 lanes x 16 B = 512 B store
        ushort8 h;
        if (use_sub) {
            ushort8 s = *(const ushort8*)&subb[(size_t)n * KT + cb];
#pragma unroll
            for (int q = 0; q < 8; ++q)
                h[q] = f2bf(alpha * a[q] - bf2f(s[q]));
        } else {
#pragma unroll
            for (int q = 0; q < 8; ++q)
                h[q] = f2bf(alpha * a[q]);
        }
        *(ushort8*)&outb[(size_t)n * KT + cb] = h;
    }
}

// ---------------- fused bf16 MFMA GEMM (3-buffer, counted-vmcnt pipeline) ----------------
// out[M=40000][256] = Abf[M][1280] @ WT^T + bias.  (round-1 form, best mean 44.4 us)
// CONCLUSION r0-r4: every schedule/tile/layout variant lands at 44-46 us =
// 143 MB mixed HBM traffic at ~3.25 TB/s. This kernel is at its byte floor.
__global__ __launch_bounds__(256, 2)
void gemm_mfma(const bf16_t* __restrict__ Abf,  // [NN][KT]
               const bf16_t* __restrict__ WT,   // [256][KT]
               const float* __restrict__ bias,
               float* __restrict__ out) {
    __shared__ bf16_t smem[3][12288];  // per buf: As = [0,4096), Bs = [4096,12288)
    int tid = threadIdx.x;
    int w = tid >> 6, lane = tid & 63;
    int m0 = blockIdx.x * 64;
    int n0 = blockIdx.y * 128;
    int wm = w & 1, wn = w >> 1;
    int quad = lane >> 4, l16 = lane & 15, l7 = l16 & 7;

    // staging: 1536 granules of 16B per K-iter; wave w call j covers
    // granules gi = (w*6+j)*64 + lane. gi<512 -> A slot, else B slot.
    const bf16_t* srcbase[6];
#pragma unroll
    for (int j = 0; j < 6; ++j) {
        int gi = (w * 6 + j) * 64 + lane;           // 0..1535
        int isB = gi >= 512;
        int t  = isB ? gi - 512 : gi;
        int row = t >> 3;                           // A: 0..63, B: 0..127
        int pg = t & 7;
        int g  = pg ^ (row & 7);                    // physical k-granule slot
        srcbase[j] = (isB ? WT + (size_t)(n0 + row) * KT
                          : Abf + (size_t)(m0 + row) * KT) + g * 8;
    }

    int arowb = wm * 32 + l16;    // A fragment base row (mt adds 16)
    int browb = wn * 64 + l16;    // B fragment base row (nt adds 16)

    floatx4 acc[2][4] = {};

    const int NT = KT / 64;       // 20

    // prologue: issue tiles 0 and 1 (12 loads/wave outstanding)
#pragma unroll
    for (int j = 0; j < 6; ++j)
        GLL16(srcbase[j] + 0 * 64, &smem[0][(w * 6 + j) * 512]);
#pragma unroll
    for (int j = 0; j < 6; ++j)
        GLL16(srcbase[j] + 1 * 64, &smem[1][(w * 6 + j) * 512]);

    int bufc = 0;                 // buffer holding tile t
    for (int t = 0; t < NT; ++t) {
        // wait: tile t's 6 loads (oldest outstanding) have landed in LDS
        if (t < NT - 1) {
            asm volatile("s_waitcnt vmcnt(6)" ::: "memory");
        } else {
            asm volatile("s_waitcnt vmcnt(0)" ::: "memory");
        }
        __builtin_amdgcn_sched_barrier(0);
        __builtin_amdgcn_s_barrier();   // all waves: tile t landed; buf[(t-1)%3] reads done

        // issue tile t+2 into buf[(t+2)%3] (== buf[(t-1)%3], safe after barrier)
        if (t + 2 < NT) {
            int bnext = bufc + 2; if (bnext >= 3) bnext -= 3;
#pragma unroll
            for (int j = 0; j < 6; ++j)
                GLL16(srcbase[j] + (t + 2) * 64, &smem[bnext][(w * 6 + j) * 512]);
        }

        const bf16_t* sb = smem[bufc];
#pragma unroll
        for (int c = 0; c < 2; ++c) {              // two 32-k chunks inside BK=64
            int gp   = (c * 4 + quad) ^ l7;        // physical granule for this frag
            int aoff = (arowb * 8 + gp) * 8;
            int boff = 4096 + (browb * 8 + gp) * 8;
            short8 af[2], bfr[4];
#pragma unroll
            for (int mt = 0; mt < 2; ++mt) af[mt]  = *(const short8*)&sb[aoff + mt * 1024];
#pragma unroll
            for (int nt = 0; nt < 4; ++nt) bfr[nt] = *(const short8*)&sb[boff + nt * 1024];
#pragma unroll
            for (int mt = 0; mt < 2; ++mt)
#pragma unroll
                for (int nt = 0; nt < 4; ++nt)
                    acc[mt][nt] = __builtin_amdgcn_mfma_f32_16x16x32_bf16(
                        af[mt], bfr[nt], acc[mt][nt], 0, 0, 0);
        }

        bufc += 1; if (bufc == 3) bufc = 0;
    }

    // epilogue: C/D layout col=lane&15, row=quad*4+reg  (m89-verified)
#pragma unroll
    for (int nt = 0; nt < 4; ++nt) {
        int n = n0 + wn * 64 + nt * 16 + l16;
        float bv = bias[n];
#pragma unroll
        for (int mt = 0; mt < 2; ++mt) {
            int mbase = m0 + wm * 32 + mt * 16 + quad * 4;
#pragma unroll
            for (int r = 0; r < 4; ++r)
                out[(size_t)(mbase + r) * C + n] = acc[mt][nt][r] + bv;
        }
    }
}

// ---------------- launch ----------------

extern "C" void kernel_launch(void* const* d_in, const int* in_sizes, int n_in,
                              void* d_out, int out_size, void* d_ws, size_t ws_size,
                              hipStream_t stream) {
    const float* x    = (const float*)d_in[0];
    const int*   ei   = (const int*)d_in[1];
    const float* ew   = (const float*)d_in[2];
    const float* W    = (const float*)d_in[3];   // [5][256][256]
    const float* bias = (const float*)d_in[4];
    float* out = (float*)d_out;

    char* p = (char*)d_ws;
    auto carve = [&](size_t bytes) {
        char* q = p;
        p += (bytes + 255) & ~(size_t)255;
        return q;
    };
    int*    deg     = (int*)   carve(NN * 4);
    int*    cnt     = (int*)   carve(NN * 4);
    int*    incl    = (int*)   carve(NN * 4);
    int*    bsum    = (int*)   carve(256 * 4);
    int*    row_ptr = (int*)   carve((NN + 1) * 4);
    int*    cursor  = (int*)   carve(NN * 4);
    int*    csr_col = (int*)   carve(NE * 4);
    float*  csr_val = (float*) carve(NE * 4);
    float*  dis     = (float*) carve(NN * 4);
    bf16_t* abf     = (bf16_t*)carve((size_t)NN * KT * 2);   // fused bf16 A (recursion state)
    bf16_t* WT      = (bf16_t*)carve((size_t)C * KT * 2);    // W transposed bf16
    (void)ws_size; (void)n_in; (void)in_sizes; (void)out_size;

    const int NB_E = (NE + 255) / 256;   // 1250
    const int NB_N = (NN + 255) / 256;   // 157

    hipMemsetAsync(deg, 0, NN * 4, stream);
    hipMemsetAsync(cnt, 0, NN * 4, stream);

    count_kernel<<<NB_E, 256, 0, stream>>>(ei, deg, cnt);
    scan1_kernel<<<NB_N, 256, 0, stream>>>(cnt, incl, bsum);
    scan2_kernel<<<1, 256, 0, stream>>>(bsum, NB_N);
    scan3_kernel<<<NB_N, 256, 0, stream>>>(cnt, incl, bsum, deg, dis, row_ptr, cursor);
    fill_kernel<<<NB_E, 256, 0, stream>>>(ei, ew, dis, cursor, csr_col, csr_val);

    convx_kernel<<<(NN * 64 + 255) / 256, 256, 0, stream>>>(x, abf);
    wt_kernel<<<(256 * KT + 255) / 256, 256, 0, stream>>>(W, WT);

    // Chebyshev recursion, bf16 state in abf chunks 0..4 (chunk k at abf + k*256)
    spmm_kernel<<<NN / 4, 256, 0, stream>>>(abf + 0 * 256, nullptr, row_ptr, csr_col,
                                            csr_val, abf + 1 * 256, 1.0f, 0);
    spmm_kernel<<<NN / 4, 256, 0, stream>>>(abf + 1 * 256, abf + 0 * 256, row_ptr,
                                            csr_col, csr_val, abf + 2 * 256, 2.0f, 1);
    spmm_kernel<<<NN / 4, 256, 0, stream>>>(abf + 2 * 256, abf + 1 * 256, row_ptr,
                                            csr_col, csr_val, abf + 3 * 256, 2.0f, 1);
    spmm_kernel<<<NN / 4, 256, 0, stream>>>(abf + 3 * 256, abf + 2 * 256, row_ptr,
                                            csr_col, csr_val, abf + 4 * 256, 2.0f, 1);

    // fused GEMM: out = abf @ WT^T + bias
    dim3 ggrid(625, 2);
    gemm_mfma<<<ggrid, 256, 0, stream>>>(abf, WT, bias, out);
}